// Round 1
// baseline (7924.697 us; speedup 1.0000x reference)
//
#include <hip/hip_runtime.h>
#include <math.h>

typedef unsigned short u16;
typedef __attribute__((ext_vector_type(8))) short short8;
typedef __attribute__((ext_vector_type(4))) float floatx4;

constexpr int kIMG = 224;
constexpr int kD   = 768;
constexpr int kS   = 197;   // tokens incl CLS
constexpr int kB   = 32;
constexpr int kNH  = 12;
constexpr int kF   = 3072;
constexpr int kN   = 196;   // fixations
constexpr int kNL  = 1000;
constexpr int kM     = kB * kS;   // 6304
constexpr int kMPAD  = 6400;      // padded rows so GEMM needs no guards
constexpr int kMPATCH = kB * kN;  // 6272 = 49*128 exactly

__device__ __forceinline__ float bf2f(u16 v) { return __uint_as_float(((unsigned)v) << 16); }
__device__ __forceinline__ u16 f2bf(float x) {
    unsigned u = __float_as_uint(x);
    u += 0x7fff + ((u >> 16) & 1);   // round-to-nearest-even
    return (u16)(u >> 16);
}

// ---------------- fp32 -> bf16 plain convert ----------------
__global__ void cvt_kernel(const float* __restrict__ src, u16* __restrict__ dst, int n) {
    int i = blockIdx.x * 256 + threadIdx.x;
    if (i < n) dst[i] = f2bf(src[i]);
}

// ---------------- fp32 [R,C] -> bf16 [C,R] tiled transpose ----------------
__global__ void transpose_cvt(const float* __restrict__ src, u16* __restrict__ dst, int R, int C) {
    __shared__ float tile[32][33];
    int c0 = blockIdx.x * 32, r0 = blockIdx.y * 32;
    int tx = threadIdx.x, ty = threadIdx.y;   // (32, 8)
    #pragma unroll
    for (int j = 0; j < 32; j += 8) {
        int r = r0 + ty + j, c = c0 + tx;
        tile[ty + j][tx] = (r < R && c < C) ? src[(size_t)r * C + c] : 0.f;
    }
    __syncthreads();
    #pragma unroll
    for (int j = 0; j < 32; j += 8) {
        int c = c0 + ty + j, r = r0 + tx;
        if (c < C && r < R) dst[(size_t)c * R + r] = f2bf(tile[tx][ty + j]);
    }
}

// ---------------- gather fixation patches -> bf16 [6272, 768] ----------------
__global__ void gather_kernel(const float* __restrict__ img, const int* __restrict__ locs,
                              u16* __restrict__ pbuf) {
    int t = blockIdx.x;                 // 0..6271
    int b = t / kN;
    int x = locs[(size_t)t * 2 + 0], y = locs[(size_t)t * 2 + 1];
    bool valid = (x >= 0) && (y >= 0);
    int top = y - 8, left = x - 8;
    top  = min(max(top, 0),  kIMG - 16);   // dynamic_slice clamp semantics
    left = min(max(left, 0), kIMG - 16);
    const float* ib = img + (size_t)b * 3 * kIMG * kIMG;
    for (int e = threadIdx.x; e < 768; e += 64) {
        int c = e >> 8, r = (e >> 4) & 15, cc = e & 15;
        float v = valid ? ib[c * kIMG * kIMG + (top + r) * kIMG + (left + cc)] : 0.f;
        pbuf[(size_t)t * 768 + e] = f2bf(v);
    }
}

// ---------------- assemble x = concat(cls, tokens) + pos_emb (fp32) ----------------
__global__ void assemble_kernel(const u16* __restrict__ tokens, const float* __restrict__ cls,
                                const float* __restrict__ pos, float* __restrict__ xb) {
    int i = blockIdx.x * 256 + threadIdx.x;
    if (i >= kM * kD) return;
    int row = i / kD, d = i - row * kD;
    int b = row / kS, s = row - b * kS;
    float v = (s == 0) ? cls[d] : bf2f(tokens[((size_t)(b * kN + s - 1)) * kD + d]);
    xb[i] = v + pos[(size_t)s * kD + d];
}

// ---------------- LayerNorm fp32 -> bf16 (D=768, block=256) ----------------
__global__ __launch_bounds__(256) void ln_kernel(const float* __restrict__ x, u16* __restrict__ outp,
                                                 const float* __restrict__ g, const float* __restrict__ bb) {
    __shared__ float sm[4];
    int row = blockIdx.x, tid = threadIdx.x;
    const float* xr = x + (size_t)row * kD;
    float v0 = xr[tid], v1 = xr[tid + 256], v2 = xr[tid + 512];
    float s = v0 + v1 + v2;
    #pragma unroll
    for (int o = 32; o > 0; o >>= 1) s += __shfl_down(s, o, 64);
    if ((tid & 63) == 0) sm[tid >> 6] = s;
    __syncthreads();
    float mu = (sm[0] + sm[1] + sm[2] + sm[3]) * (1.f / 768.f);
    __syncthreads();
    float d0 = v0 - mu, d1 = v1 - mu, d2 = v2 - mu;
    float sq = d0 * d0 + d1 * d1 + d2 * d2;
    #pragma unroll
    for (int o = 32; o > 0; o >>= 1) sq += __shfl_down(sq, o, 64);
    if ((tid & 63) == 0) sm[tid >> 6] = sq;
    __syncthreads();
    float var = (sm[0] + sm[1] + sm[2] + sm[3]) * (1.f / 768.f);
    float rs = rsqrtf(var + 1e-12f);
    u16* orow = outp + (size_t)row * kD;
    orow[tid]       = f2bf(d0 * rs * g[tid]       + bb[tid]);
    orow[tid + 256] = f2bf(d1 * rs * g[tid + 256] + bb[tid + 256]);
    orow[tid + 512] = f2bf(d2 * rs * g[tid + 512] + bb[tid + 512]);
}

// ---------------- bf16 MFMA GEMM: C[M,N] = A[M,K] @ Bt[N,K]^T (+bias, epilogue) ----------------
// EPI: 0 = bias only, 1 = bias+GELU(exact), 2 = bias+residual add
// OUTBF: 1 = bf16 out, 0 = fp32 out
// No bounds guards: caller guarantees A/C/resid buffers have >= gridDim.x*128 rows.
template <int EPI, int OUTBF>
__global__ __launch_bounds__(256) void gemm_bt(const u16* __restrict__ A, const u16* __restrict__ Bt,
                                               u16* Cb, float* Cf,
                                               const float* __restrict__ bias, const float* resid,
                                               int N, int K) {
    __shared__ u16 sA[128 * 32];
    __shared__ u16 sB[128 * 32];
    int tid = threadIdx.x;
    int lane = tid & 63, w = tid >> 6;
    int wm = w >> 1, wn = w & 1;
    int m0 = blockIdx.x * 128, n0 = blockIdx.y * 128;
    floatx4 acc[4][4] = {};

    const int rowS = tid >> 1;
    const int colS = (tid & 1) * 16;
    const int kq = lane >> 4;     // 0..3
    const int mr = lane & 15;

    for (int k0 = 0; k0 < K; k0 += 32) {
        const u16* pa = A  + (size_t)(m0 + rowS) * K + k0 + colS;
        const u16* pb = Bt + (size_t)(n0 + rowS) * K + k0 + colS;
        uint4 a0 = *(const uint4*)pa, a1 = *(const uint4*)(pa + 8);
        uint4 b0 = *(const uint4*)pb, b1 = *(const uint4*)(pb + 8);
        __syncthreads();   // previous compute done before overwriting LDS
        *(uint4*)&sA[rowS * 32 + colS]     = a0;
        *(uint4*)&sA[rowS * 32 + colS + 8] = a1;
        *(uint4*)&sB[rowS * 32 + colS]     = b0;
        *(uint4*)&sB[rowS * 32 + colS + 8] = b1;
        __syncthreads();
        short8 af[4], bf[4];
        #pragma unroll
        for (int i = 0; i < 4; i++) {
            int mloc = wm * 64 + i * 16 + mr;
            af[i] = *(const short8*)&sA[mloc * 32 + kq * 8];
            int nloc = wn * 64 + i * 16 + mr;
            bf[i] = *(const short8*)&sB[nloc * 32 + kq * 8];
        }
        #pragma unroll
        for (int i = 0; i < 4; i++)
            #pragma unroll
            for (int j = 0; j < 4; j++)
                acc[i][j] = __builtin_amdgcn_mfma_f32_16x16x32_bf16(af[i], bf[j], acc[i][j], 0, 0, 0);
    }

    int cr = (lane >> 4) * 4;   // C/D: row = (lane>>4)*4 + reg, col = lane&15
    int cc = lane & 15;
    #pragma unroll
    for (int i = 0; i < 4; i++) {
        #pragma unroll
        for (int j = 0; j < 4; j++) {
            int n = n0 + wn * 64 + j * 16 + cc;
            float bv = bias[n];
            #pragma unroll
            for (int t = 0; t < 4; t++) {
                int m = m0 + wm * 64 + i * 16 + cr + t;
                float v = acc[i][j][t] + bv;
                if (EPI == 1) v = 0.5f * v * (1.f + erff(v * 0.70710678118654752f));
                if (EPI == 2) v += resid[(size_t)m * N + n];
                if (OUTBF) Cb[(size_t)m * N + n] = f2bf(v);
                else       Cf[(size_t)m * N + n] = v;
            }
        }
    }
}

// ---------------- attention: per (b,h) block, K in LDS, 1 query/wave ----------------
__global__ __launch_bounds__(256) void attn_kernel(const u16* __restrict__ qkv, u16* __restrict__ outp) {
    __shared__ u16 sK[197 * 72];   // pitch 72 breaks 128B-stride bank aliasing
    int bh = blockIdx.x;
    int b = bh / kNH, h = bh % kNH;
    int tid = threadIdx.x, w = tid >> 6, lane = tid & 63;
    int ks = lane >> 3, dc = lane & 7;
    const u16* qb = qkv + (size_t)b * kS * 2304;
    for (int idx = tid; idx < kS * 8; idx += 256) {
        int r = idx >> 3, c = idx & 7;
        *(uint4*)&sK[r * 72 + c * 8] = *(const uint4*)&qb[(size_t)r * 2304 + 768 + h * 64 + c * 8];
    }
    __syncthreads();
    for (int q = w; q < kS; q += 4) {
        float qv[8];
        {
            uint4 t4 = *(const uint4*)&qb[(size_t)q * 2304 + h * 64 + dc * 8];
            const u16* u = (const u16*)&t4;
            #pragma unroll
            for (int j = 0; j < 8; j++) qv[j] = bf2f(u[j]);
        }
        float sc[25];
        #pragma unroll
        for (int i = 0; i < 25; i++) {
            int key = i * 8 + ks;
            float dot = 0.f;
            if (key < kS) {
                uint4 t4 = *(const uint4*)&sK[key * 72 + dc * 8];
                const u16* u = (const u16*)&t4;
                #pragma unroll
                for (int j = 0; j < 8; j++) dot += qv[j] * bf2f(u[j]);
            }
            dot += __shfl_xor(dot, 1, 64);
            dot += __shfl_xor(dot, 2, 64);
            dot += __shfl_xor(dot, 4, 64);
            sc[i] = (key < kS) ? dot * 0.125f : -1e30f;
        }
        float mx = -1e30f;
        #pragma unroll
        for (int i = 0; i < 25; i++) mx = fmaxf(mx, sc[i]);
        mx = fmaxf(mx, __shfl_xor(mx, 8, 64));
        mx = fmaxf(mx, __shfl_xor(mx, 16, 64));
        mx = fmaxf(mx, __shfl_xor(mx, 32, 64));
        float sum = 0.f;
        #pragma unroll
        for (int i = 0; i < 25; i++) { float e = expf(sc[i] - mx); sc[i] = e; sum += e; }
        sum += __shfl_xor(sum, 8, 64);
        sum += __shfl_xor(sum, 16, 64);
        sum += __shfl_xor(sum, 32, 64);
        float inv = 1.f / sum;
        float o[8];
        #pragma unroll
        for (int j = 0; j < 8; j++) o[j] = 0.f;
        #pragma unroll
        for (int i = 0; i < 25; i++) {
            int key = i * 8 + ks;
            if (key < kS) {
                uint4 t4 = *(const uint4*)&qb[(size_t)key * 2304 + 1536 + h * 64 + dc * 8];
                const u16* u = (const u16*)&t4;
                #pragma unroll
                for (int j = 0; j < 8; j++) o[j] += sc[i] * bf2f(u[j]);
            }
        }
        #pragma unroll
        for (int j = 0; j < 8; j++) {
            o[j] += __shfl_xor(o[j], 8, 64);
            o[j] += __shfl_xor(o[j], 16, 64);
            o[j] += __shfl_xor(o[j], 32, 64);
        }
        if (ks == 0) {
            u16 ov[8];
            #pragma unroll
            for (int j = 0; j < 8; j++) ov[j] = f2bf(o[j] * inv);
            *(uint4*)&outp[((size_t)b * kS + q) * kD + h * 64 + dc * 8] = *(uint4*)ov;
        }
    }
}

// ---------------- classifier: logits[b,o] = lnf(x_cls) . cls_w[o] + cls_b[o] ----------------
__global__ __launch_bounds__(256) void cls_kernel(const u16* __restrict__ xf, const u16* __restrict__ wb,
                                                  const float* __restrict__ cb, float* __restrict__ outp) {
    __shared__ float sx[kD];
    int b = blockIdx.x, tid = threadIdx.x;
    const u16* xr = xf + (size_t)b * kS * kD;   // CLS row
    for (int i = tid; i < kD; i += 256) sx[i] = bf2f(xr[i]);
    __syncthreads();
    for (int o = tid; o < kNL; o += 256) {
        const u16* wr = wb + (size_t)o * kD;
        float acc = 0.f;
        for (int kk = 0; kk < kD; kk += 8) {
            uint4 t4 = *(const uint4*)&wr[kk];
            const u16* u = (const u16*)&t4;
            #pragma unroll
            for (int j = 0; j < 8; j++) acc += sx[kk + j] * bf2f(u[j]);
        }
        outp[(size_t)b * kNL + o] = acc + cb[o];
    }
}

extern "C" void kernel_launch(void* const* d_in, const int* in_sizes, int n_in,
                              void* d_out, int out_size, void* d_ws, size_t ws_size,
                              hipStream_t stream) {
    const float* pixel   = (const float*)d_in[0];
    const int*   locs    = (const int*)d_in[1];
    const float* patch_w = (const float*)d_in[2];
    const float* patch_b = (const float*)d_in[3];
    const float* cls_tok = (const float*)d_in[4];
    const float* pos_emb = (const float*)d_in[5];
    const float* ln1_g   = (const float*)d_in[6];
    const float* ln1_b   = (const float*)d_in[7];
    const float* wqkv    = (const float*)d_in[8];
    const float* bqkv    = (const float*)d_in[9];
    const float* wo      = (const float*)d_in[10];
    const float* bo      = (const float*)d_in[11];
    const float* ln2_g   = (const float*)d_in[12];
    const float* ln2_b   = (const float*)d_in[13];
    const float* w1      = (const float*)d_in[14];
    const float* b1      = (const float*)d_in[15];
    const float* w2      = (const float*)d_in[16];
    const float* b2      = (const float*)d_in[17];
    const float* lnf_g   = (const float*)d_in[18];
    const float* lnf_b   = (const float*)d_in[19];
    const float* cls_w   = (const float*)d_in[20];
    const float* cls_b   = (const float*)d_in[21];
    float* out = (float*)d_out;

    // workspace layout (bytes), all 256B-aligned; total ~85.7 MB
    char* ws = (char*)d_ws;
    float* xb  = (float*)(ws + 0);                      // [6400, 768]  fp32 residual stream
    u16*   hb  = (u16*)(ws + 19660800);                 // [6400, 768]  bf16
    u16*   big = (u16*)(ws + 29491200);                 // [6400, 3072] bf16 (qkv / mlp hidden / patches)
    u16*   wl  = (u16*)(ws + 68812800);                 // 7,077,888 bf16: per-layer transposed weights
    u16*   pwb = (u16*)(ws + 82968576);                 // patch_w bf16 [768(N),768(K)] (already N,K)
    u16*   cwb = (u16*)(ws + 84148224);                 // cls_w bf16 [1000,768]
    u16*   pbuf = big;                                  // gathered patches alias [6272,768]

    const size_t oQKV = 0, oWO = 1769472, oW1 = 2359296, oW2 = 4718592;

    cvt_kernel<<<2304, 256, 0, stream>>>(patch_w, pwb, 768 * 768);
    cvt_kernel<<<3000, 256, 0, stream>>>(cls_w, cwb, kNL * 768);
    gather_kernel<<<kMPATCH, 64, 0, stream>>>(pixel, locs, pbuf);
    // tokens = patches @ patch_w^T + patch_b  -> hb [6272,768]
    gemm_bt<0, 1><<<dim3(49, 6), 256, 0, stream>>>(pbuf, pwb, hb, nullptr, patch_b, nullptr, 768, 768);
    assemble_kernel<<<(kM * kD + 255) / 256, 256, 0, stream>>>(hb, cls_tok, pos_emb, xb);

    for (int l = 0; l < 12; l++) {
        transpose_cvt<<<dim3(72, 24), dim3(32, 8), 0, stream>>>(wqkv + (size_t)l * 768 * 2304, wl + oQKV, 768, 2304);
        transpose_cvt<<<dim3(24, 24), dim3(32, 8), 0, stream>>>(wo   + (size_t)l * 768 * 768,  wl + oWO,  768, 768);
        transpose_cvt<<<dim3(96, 24), dim3(32, 8), 0, stream>>>(w1   + (size_t)l * 768 * 3072, wl + oW1,  768, 3072);
        transpose_cvt<<<dim3(24, 96), dim3(32, 8), 0, stream>>>(w2   + (size_t)l * 3072 * 768, wl + oW2,  3072, 768);

        ln_kernel<<<kM, 256, 0, stream>>>(xb, hb, ln1_g + l * 768, ln1_b + l * 768);
        // qkv = h @ wqkv + bqkv -> big [*,2304] bf16
        gemm_bt<0, 1><<<dim3(50, 18), 256, 0, stream>>>(hb, wl + oQKV, big, nullptr, bqkv + (size_t)l * 2304, nullptr, 2304, 768);
        attn_kernel<<<kB * kNH, 256, 0, stream>>>(big, hb);
        // x += attn_out @ wo + bo   (fp32 out, in-place residual)
        gemm_bt<2, 0><<<dim3(50, 6), 256, 0, stream>>>(hb, wl + oWO, nullptr, xb, bo + (size_t)l * 768, xb, 768, 768);
        ln_kernel<<<kM, 256, 0, stream>>>(xb, hb, ln2_g + l * 768, ln2_b + l * 768);
        // mlp hidden = gelu(h @ w1 + b1) -> big [*,3072] bf16
        gemm_bt<1, 1><<<dim3(50, 24), 256, 0, stream>>>(hb, wl + oW1, big, nullptr, b1 + (size_t)l * 3072, nullptr, 3072, 768);
        // x += mlp @ w2 + b2
        gemm_bt<2, 0><<<dim3(50, 6), 256, 0, stream>>>(big, wl + oW2, nullptr, xb, b2 + (size_t)l * 768, xb, 768, 3072);
    }

    ln_kernel<<<kM, 256, 0, stream>>>(xb, hb, lnf_g, lnf_b);
    cls_kernel<<<kB, 256, 0, stream>>>(hb, cwb, cls_b, out);
}

// Round 2
// 6152.708 us; speedup vs baseline: 1.2880x; 1.2880x over previous
//
#include <hip/hip_runtime.h>
#include <math.h>

typedef unsigned short u16;
typedef __attribute__((ext_vector_type(8))) short short8;
typedef __attribute__((ext_vector_type(4))) float floatx4;

constexpr int kIMG = 224;
constexpr int kD   = 768;
constexpr int kS   = 197;   // tokens incl CLS
constexpr int kB   = 32;
constexpr int kNH  = 12;
constexpr int kF   = 3072;
constexpr int kN   = 196;   // fixations
constexpr int kNL  = 1000;
constexpr int kM     = kB * kS;   // 6304
constexpr int kMPAD  = 6400;      // padded rows so GEMM needs no guards
constexpr int kMPATCH = kB * kN;  // 6272 = 49*128 exactly

__device__ __forceinline__ float bf2f(u16 v) { return __uint_as_float(((unsigned)v) << 16); }
__device__ __forceinline__ u16 f2bf(float x) {
    unsigned u = __float_as_uint(x);
    u += 0x7fff + ((u >> 16) & 1);   // round-to-nearest-even
    return (u16)(u >> 16);
}

// async global->LDS 16B copy. HW semantics: per wave, data lands at
// (first-lane lds addr) + lane*16 — caller must pass lane-linear lds ptrs.
__device__ __forceinline__ void async_copy16(const u16* gsrc, u16* ldst) {
    __builtin_amdgcn_global_load_lds(
        (const __attribute__((address_space(1))) unsigned int*)gsrc,
        (__attribute__((address_space(3))) unsigned int*)ldst,
        16, 0, 0);
}

// ---------------- fp32 -> bf16 plain convert ----------------
__global__ void cvt_kernel(const float* __restrict__ src, u16* __restrict__ dst, int n) {
    int i = blockIdx.x * 256 + threadIdx.x;
    if (i < n) dst[i] = f2bf(src[i]);
}

// ---------------- fp32 [R,C] -> bf16 [C,R] tiled transpose ----------------
__global__ void transpose_cvt(const float* __restrict__ src, u16* __restrict__ dst, int R, int C) {
    __shared__ float tile[32][33];
    int c0 = blockIdx.x * 32, r0 = blockIdx.y * 32;
    int tx = threadIdx.x, ty = threadIdx.y;   // (32, 8)
    #pragma unroll
    for (int j = 0; j < 32; j += 8) {
        int r = r0 + ty + j, c = c0 + tx;
        tile[ty + j][tx] = (r < R && c < C) ? src[(size_t)r * C + c] : 0.f;
    }
    __syncthreads();
    #pragma unroll
    for (int j = 0; j < 32; j += 8) {
        int c = c0 + ty + j, r = r0 + tx;
        if (c < C && r < R) dst[(size_t)c * R + r] = f2bf(tile[tx][ty + j]);
    }
}

// ---------------- gather fixation patches -> bf16 [6272, 768] ----------------
__global__ void gather_kernel(const float* __restrict__ img, const int* __restrict__ locs,
                              u16* __restrict__ pbuf) {
    int t = blockIdx.x;                 // 0..6271
    int b = t / kN;
    int x = locs[(size_t)t * 2 + 0], y = locs[(size_t)t * 2 + 1];
    bool valid = (x >= 0) && (y >= 0);
    int top = y - 8, left = x - 8;
    top  = min(max(top, 0),  kIMG - 16);   // dynamic_slice clamp semantics
    left = min(max(left, 0), kIMG - 16);
    const float* ib = img + (size_t)b * 3 * kIMG * kIMG;
    for (int e = threadIdx.x; e < 768; e += 64) {
        int c = e >> 8, r = (e >> 4) & 15, cc = e & 15;
        float v = valid ? ib[c * kIMG * kIMG + (top + r) * kIMG + (left + cc)] : 0.f;
        pbuf[(size_t)t * 768 + e] = f2bf(v);
    }
}

// ---------------- assemble x = concat(cls, tokens) + pos_emb (fp32) ----------------
__global__ void assemble_kernel(const u16* __restrict__ tokens, const float* __restrict__ cls,
                                const float* __restrict__ pos, float* __restrict__ xb) {
    int i = blockIdx.x * 256 + threadIdx.x;
    if (i >= kM * kD) return;
    int row = i / kD, d = i - row * kD;
    int b = row / kS, s = row - b * kS;
    float v = (s == 0) ? cls[d] : bf2f(tokens[((size_t)(b * kN + s - 1)) * kD + d]);
    xb[i] = v + pos[(size_t)s * kD + d];
}

// ---------------- LayerNorm fp32 -> bf16 (D=768, block=256) ----------------
__global__ __launch_bounds__(256) void ln_kernel(const float* __restrict__ x, u16* __restrict__ outp,
                                                 const float* __restrict__ g, const float* __restrict__ bb) {
    __shared__ float sm[4];
    int row = blockIdx.x, tid = threadIdx.x;
    const float* xr = x + (size_t)row * kD;
    float v0 = xr[tid], v1 = xr[tid + 256], v2 = xr[tid + 512];
    float s = v0 + v1 + v2;
    #pragma unroll
    for (int o = 32; o > 0; o >>= 1) s += __shfl_down(s, o, 64);
    if ((tid & 63) == 0) sm[tid >> 6] = s;
    __syncthreads();
    float mu = (sm[0] + sm[1] + sm[2] + sm[3]) * (1.f / 768.f);
    __syncthreads();
    float d0 = v0 - mu, d1 = v1 - mu, d2 = v2 - mu;
    float sq = d0 * d0 + d1 * d1 + d2 * d2;
    #pragma unroll
    for (int o = 32; o > 0; o >>= 1) sq += __shfl_down(sq, o, 64);
    if ((tid & 63) == 0) sm[tid >> 6] = sq;
    __syncthreads();
    float var = (sm[0] + sm[1] + sm[2] + sm[3]) * (1.f / 768.f);
    float rs = rsqrtf(var + 1e-12f);
    u16* orow = outp + (size_t)row * kD;
    orow[tid]       = f2bf(d0 * rs * g[tid]       + bb[tid]);
    orow[tid + 256] = f2bf(d1 * rs * g[tid + 256] + bb[tid + 256]);
    orow[tid + 512] = f2bf(d2 * rs * g[tid + 512] + bb[tid + 512]);
}

// ---------------- bf16 MFMA GEMM: C[M,N] = A[M,K] @ Bt[N,K]^T (+bias, epilogue) ----------------
// EPI: 0 = bias only, 1 = bias+GELU(exact), 2 = bias+residual add
// OUTBF: 1 = bf16 out, 0 = fp32 out
// Staging via global_load_lds width=16 (m97 pattern); no bounds guards — caller
// guarantees A/C/resid buffers have >= gridDim.x*128 rows.
template <int EPI, int OUTBF>
__global__ __launch_bounds__(256) void gemm_bt(const u16* __restrict__ A, const u16* __restrict__ Bt,
                                               u16* Cb, float* Cf,
                                               const float* __restrict__ bias, const float* resid,
                                               int N, int K) {
    __shared__ u16 sA[128 * 32];
    __shared__ u16 sB[128 * 32];
    int tid = threadIdx.x;
    int lane = tid & 63, w = tid >> 6;
    int wm = w >> 1, wn = w & 1;
    int m0 = blockIdx.x * 128, n0 = blockIdx.y * 128;
    floatx4 acc[4][4] = {};

    // lane-linear staging map: thread tid covers 16B at LDS byte offset tid*16
    // (within wave: base + lane*16 — required by global_load_lds HW semantics)
    const int rS = tid >> 2;            // 0..63
    const int cS = (tid & 3) * 8;       // element col
    const int kq = lane >> 4;           // 0..3
    const int mr = lane & 15;

    for (int k0 = 0; k0 < K; k0 += 32) {
        __syncthreads();   // prior iteration's LDS reads complete before overwrite
        async_copy16(A  + (size_t)(m0 + rS)      * K + k0 + cS, &sA[rS * 32 + cS]);
        async_copy16(A  + (size_t)(m0 + 64 + rS) * K + k0 + cS, &sA[(64 + rS) * 32 + cS]);
        async_copy16(Bt + (size_t)(n0 + rS)      * K + k0 + cS, &sB[rS * 32 + cS]);
        async_copy16(Bt + (size_t)(n0 + 64 + rS) * K + k0 + cS, &sB[(64 + rS) * 32 + cS]);
        __syncthreads();   // drains vmcnt -> LDS data visible
        short8 af[4], bf[4];
        #pragma unroll
        for (int i = 0; i < 4; i++) {
            int mloc = wm * 64 + i * 16 + mr;
            af[i] = *(const short8*)&sA[mloc * 32 + kq * 8];
            int nloc = wn * 64 + i * 16 + mr;
            bf[i] = *(const short8*)&sB[nloc * 32 + kq * 8];
        }
        #pragma unroll
        for (int i = 0; i < 4; i++)
            #pragma unroll
            for (int j = 0; j < 4; j++)
                acc[i][j] = __builtin_amdgcn_mfma_f32_16x16x32_bf16(af[i], bf[j], acc[i][j], 0, 0, 0);
    }

    int cr = (lane >> 4) * 4;   // C/D: row = (lane>>4)*4 + reg, col = lane&15
    int cc = lane & 15;
    #pragma unroll
    for (int i = 0; i < 4; i++) {
        #pragma unroll
        for (int j = 0; j < 4; j++) {
            int n = n0 + wn * 64 + j * 16 + cc;
            float bv = bias[n];
            #pragma unroll
            for (int t = 0; t < 4; t++) {
                int m = m0 + wm * 64 + i * 16 + cr + t;
                float v = acc[i][j][t] + bv;
                if (EPI == 1) v = 0.5f * v * (1.f + erff(v * 0.70710678118654752f));
                if (EPI == 2) v += resid[(size_t)m * N + n];
                if (OUTBF) Cb[(size_t)m * N + n] = f2bf(v);
                else       Cf[(size_t)m * N + n] = v;
            }
        }
    }
}

// ---------------- attention: block = (b,h) x 16-query tile, K in LDS ----------------
__global__ __launch_bounds__(256) void attn_kernel(const u16* __restrict__ qkv, u16* __restrict__ outp) {
    __shared__ u16 sK[197 * 72];   // pitch 72 breaks 128B-stride bank aliasing
    int bh = blockIdx.x;
    int b = bh / kNH, h = bh % kNH;
    int q0 = blockIdx.y * 16;
    int tid = threadIdx.x, w = tid >> 6, lane = tid & 63;
    int ks = lane >> 3, dc = lane & 7;
    const u16* qb = qkv + (size_t)b * kS * 2304;
    for (int idx = tid; idx < kS * 8; idx += 256) {
        int r = idx >> 3, c = idx & 7;
        *(uint4*)&sK[r * 72 + c * 8] = *(const uint4*)&qb[(size_t)r * 2304 + 768 + h * 64 + c * 8];
    }
    __syncthreads();
    #pragma unroll
    for (int qi = 0; qi < 4; qi++) {
        int q = q0 + qi * 4 + w;
        if (q >= kS) break;
        float qv[8];
        {
            uint4 t4 = *(const uint4*)&qb[(size_t)q * 2304 + h * 64 + dc * 8];
            const u16* u = (const u16*)&t4;
            #pragma unroll
            for (int j = 0; j < 8; j++) qv[j] = bf2f(u[j]);
        }
        float sc[25];
        #pragma unroll
        for (int i = 0; i < 25; i++) {
            int key = i * 8 + ks;
            float dot = 0.f;
            if (key < kS) {
                uint4 t4 = *(const uint4*)&sK[key * 72 + dc * 8];
                const u16* u = (const u16*)&t4;
                #pragma unroll
                for (int j = 0; j < 8; j++) dot += qv[j] * bf2f(u[j]);
            }
            dot += __shfl_xor(dot, 1, 64);
            dot += __shfl_xor(dot, 2, 64);
            dot += __shfl_xor(dot, 4, 64);
            sc[i] = (key < kS) ? dot * 0.125f : -1e30f;
        }
        float mx = -1e30f;
        #pragma unroll
        for (int i = 0; i < 25; i++) mx = fmaxf(mx, sc[i]);
        mx = fmaxf(mx, __shfl_xor(mx, 8, 64));
        mx = fmaxf(mx, __shfl_xor(mx, 16, 64));
        mx = fmaxf(mx, __shfl_xor(mx, 32, 64));
        float sum = 0.f;
        #pragma unroll
        for (int i = 0; i < 25; i++) { float e = expf(sc[i] - mx); sc[i] = e; sum += e; }
        sum += __shfl_xor(sum, 8, 64);
        sum += __shfl_xor(sum, 16, 64);
        sum += __shfl_xor(sum, 32, 64);
        float inv = 1.f / sum;
        float o[8];
        #pragma unroll
        for (int j = 0; j < 8; j++) o[j] = 0.f;
        #pragma unroll
        for (int i = 0; i < 25; i++) {
            int key = i * 8 + ks;
            if (key < kS) {
                uint4 t4 = *(const uint4*)&qb[(size_t)key * 2304 + 1536 + h * 64 + dc * 8];
                const u16* u = (const u16*)&t4;
                #pragma unroll
                for (int j = 0; j < 8; j++) o[j] += sc[i] * bf2f(u[j]);
            }
        }
        #pragma unroll
        for (int j = 0; j < 8; j++) {
            o[j] += __shfl_xor(o[j], 8, 64);
            o[j] += __shfl_xor(o[j], 16, 64);
            o[j] += __shfl_xor(o[j], 32, 64);
        }
        if (ks == 0) {
            u16 ov[8];
            #pragma unroll
            for (int j = 0; j < 8; j++) ov[j] = f2bf(o[j] * inv);
            *(uint4*)&outp[((size_t)b * kS + q) * kD + h * 64 + dc * 8] = *(uint4*)ov;
        }
    }
}

// ---------------- classifier: logits[b,o] = lnf(x_cls) . cls_w[o] + cls_b[o] ----------------
__global__ __launch_bounds__(256) void cls_kernel(const u16* __restrict__ xf, const u16* __restrict__ wb,
                                                  const float* __restrict__ cb, float* __restrict__ outp) {
    __shared__ float sx[kD];
    int b = blockIdx.x, tid = threadIdx.x;
    const u16* xr = xf + (size_t)b * kS * kD;   // CLS row
    for (int i = tid; i < kD; i += 256) sx[i] = bf2f(xr[i]);
    __syncthreads();
    for (int o = tid; o < kNL; o += 256) {
        const u16* wr = wb + (size_t)o * kD;
        float acc = 0.f;
        for (int kk = 0; kk < kD; kk += 8) {
            uint4 t4 = *(const uint4*)&wr[kk];
            const u16* u = (const u16*)&t4;
            #pragma unroll
            for (int j = 0; j < 8; j++) acc += sx[kk + j] * bf2f(u[j]);
        }
        outp[(size_t)b * kNL + o] = acc + cb[o];
    }
}

extern "C" void kernel_launch(void* const* d_in, const int* in_sizes, int n_in,
                              void* d_out, int out_size, void* d_ws, size_t ws_size,
                              hipStream_t stream) {
    const float* pixel   = (const float*)d_in[0];
    const int*   locs    = (const int*)d_in[1];
    const float* patch_w = (const float*)d_in[2];
    const float* patch_b = (const float*)d_in[3];
    const float* cls_tok = (const float*)d_in[4];
    const float* pos_emb = (const float*)d_in[5];
    const float* ln1_g   = (const float*)d_in[6];
    const float* ln1_b   = (const float*)d_in[7];
    const float* wqkv    = (const float*)d_in[8];
    const float* bqkv    = (const float*)d_in[9];
    const float* wo      = (const float*)d_in[10];
    const float* bo      = (const float*)d_in[11];
    const float* ln2_g   = (const float*)d_in[12];
    const float* ln2_b   = (const float*)d_in[13];
    const float* w1      = (const float*)d_in[14];
    const float* b1      = (const float*)d_in[15];
    const float* w2      = (const float*)d_in[16];
    const float* b2      = (const float*)d_in[17];
    const float* lnf_g   = (const float*)d_in[18];
    const float* lnf_b   = (const float*)d_in[19];
    const float* cls_w   = (const float*)d_in[20];
    const float* cls_b   = (const float*)d_in[21];
    float* out = (float*)d_out;

    // workspace layout (bytes), all 256B-aligned; total ~85.7 MB
    char* ws = (char*)d_ws;
    float* xb  = (float*)(ws + 0);                      // [6400, 768]  fp32 residual stream
    u16*   hb  = (u16*)(ws + 19660800);                 // [6400, 768]  bf16
    u16*   big = (u16*)(ws + 29491200);                 // [6400, 3072] bf16 (qkv / mlp hidden / patches)
    u16*   wl  = (u16*)(ws + 68812800);                 // 7,077,888 bf16: per-layer transposed weights
    u16*   pwb = (u16*)(ws + 82968576);                 // patch_w bf16 [768(N),768(K)] (already N,K)
    u16*   cwb = (u16*)(ws + 84148224);                 // cls_w bf16 [1000,768]
    u16*   pbuf = big;                                  // gathered patches alias [6272,768]

    const size_t oQKV = 0, oWO = 1769472, oW1 = 2359296, oW2 = 4718592;

    cvt_kernel<<<2304, 256, 0, stream>>>(patch_w, pwb, 768 * 768);
    cvt_kernel<<<3000, 256, 0, stream>>>(cls_w, cwb, kNL * 768);
    gather_kernel<<<kMPATCH, 64, 0, stream>>>(pixel, locs, pbuf);
    // tokens = patches @ patch_w^T + patch_b  -> hb [6272,768]
    gemm_bt<0, 1><<<dim3(49, 6), 256, 0, stream>>>(pbuf, pwb, hb, nullptr, patch_b, nullptr, 768, 768);
    assemble_kernel<<<(kM * kD + 255) / 256, 256, 0, stream>>>(hb, cls_tok, pos_emb, xb);

    for (int l = 0; l < 12; l++) {
        transpose_cvt<<<dim3(72, 24), dim3(32, 8), 0, stream>>>(wqkv + (size_t)l * 768 * 2304, wl + oQKV, 768, 2304);
        transpose_cvt<<<dim3(24, 24), dim3(32, 8), 0, stream>>>(wo   + (size_t)l * 768 * 768,  wl + oWO,  768, 768);
        transpose_cvt<<<dim3(96, 24), dim3(32, 8), 0, stream>>>(w1   + (size_t)l * 768 * 3072, wl + oW1,  768, 3072);
        transpose_cvt<<<dim3(24, 96), dim3(32, 8), 0, stream>>>(w2   + (size_t)l * 3072 * 768, wl + oW2,  3072, 768);

        ln_kernel<<<kM, 256, 0, stream>>>(xb, hb, ln1_g + l * 768, ln1_b + l * 768);
        // qkv = h @ wqkv + bqkv -> big [*,2304] bf16
        gemm_bt<0, 1><<<dim3(50, 18), 256, 0, stream>>>(hb, wl + oQKV, big, nullptr, bqkv + (size_t)l * 2304, nullptr, 2304, 768);
        attn_kernel<<<dim3(kB * kNH, 13), 256, 0, stream>>>(big, hb);
        // x += attn_out @ wo + bo   (fp32 out, in-place residual)
        gemm_bt<2, 0><<<dim3(50, 6), 256, 0, stream>>>(hb, wl + oWO, nullptr, xb, bo + (size_t)l * 768, xb, 768, 768);
        ln_kernel<<<kM, 256, 0, stream>>>(xb, hb, ln2_g + l * 768, ln2_b + l * 768);
        // mlp hidden = gelu(h @ w1 + b1) -> big [*,3072] bf16
        gemm_bt<1, 1><<<dim3(50, 24), 256, 0, stream>>>(hb, wl + oW1, big, nullptr, b1 + (size_t)l * 3072, nullptr, 3072, 768);
        // x += mlp @ w2 + b2
        gemm_bt<2, 0><<<dim3(50, 6), 256, 0, stream>>>(big, wl + oW2, nullptr, xb, b2 + (size_t)l * 768, xb, 768, 3072);
    }

    ln_kernel<<<kM, 256, 0, stream>>>(xb, hb, lnf_g, lnf_b);
    cls_kernel<<<kB, 256, 0, stream>>>(hb, cwb, cls_b, out);
}

// Round 3
// 4151.028 us; speedup vs baseline: 1.9091x; 1.4822x over previous
//
#include <hip/hip_runtime.h>
#include <math.h>

typedef unsigned short u16;
typedef __attribute__((ext_vector_type(8))) short short8;
typedef __attribute__((ext_vector_type(4))) float floatx4;

constexpr int kIMG = 224;
constexpr int kD   = 768;
constexpr int kS   = 197;   // tokens incl CLS
constexpr int kB   = 32;
constexpr int kNH  = 12;
constexpr int kF   = 3072;
constexpr int kN   = 196;   // fixations
constexpr int kNL  = 1000;
constexpr int kM     = kB * kS;   // 6304
constexpr int kMPAD  = 6400;      // padded rows so GEMM needs no guards
constexpr int kMPATCH = kB * kN;  // 6272 = 49*128 exactly

__device__ __forceinline__ float bf2f(u16 v) { return __uint_as_float(((unsigned)v) << 16); }
__device__ __forceinline__ u16 f2bf(float x) {
    unsigned u = __float_as_uint(x);
    u += 0x7fff + ((u >> 16) & 1);   // round-to-nearest-even
    return (u16)(u >> 16);
}

// async global->LDS 16B copy. HW semantics: per wave, data lands at
// (first-lane lds addr) + lane*16 — caller must pass lane-linear lds ptrs.
__device__ __forceinline__ void async_copy16(const u16* gsrc, u16* ldst) {
    __builtin_amdgcn_global_load_lds(
        (const __attribute__((address_space(1))) unsigned int*)gsrc,
        (__attribute__((address_space(3))) unsigned int*)ldst,
        16, 0, 0);
}

// ---------------- fp32 -> bf16 plain convert ----------------
__global__ void cvt_kernel(const float* __restrict__ src, u16* __restrict__ dst, int n) {
    int i = blockIdx.x * 256 + threadIdx.x;
    if (i < n) dst[i] = f2bf(src[i]);
}

// ---------------- fp32 [R,C] -> bf16 [C,R] tiled transpose ----------------
__global__ void transpose_cvt(const float* __restrict__ src, u16* __restrict__ dst, int R, int C) {
    __shared__ float tile[32][33];
    int c0 = blockIdx.x * 32, r0 = blockIdx.y * 32;
    int tx = threadIdx.x, ty = threadIdx.y;   // (32, 8)
    #pragma unroll
    for (int j = 0; j < 32; j += 8) {
        int r = r0 + ty + j, c = c0 + tx;
        tile[ty + j][tx] = (r < R && c < C) ? src[(size_t)r * C + c] : 0.f;
    }
    __syncthreads();
    #pragma unroll
    for (int j = 0; j < 32; j += 8) {
        int c = c0 + ty + j, r = r0 + tx;
        if (c < C && r < R) dst[(size_t)c * R + r] = f2bf(tile[tx][ty + j]);
    }
}

// ---------------- gather fixation patches -> bf16 [6272, 768] ----------------
__global__ void gather_kernel(const float* __restrict__ img, const int* __restrict__ locs,
                              u16* __restrict__ pbuf) {
    int t = blockIdx.x;                 // 0..6271
    int b = t / kN;
    int x = locs[(size_t)t * 2 + 0], y = locs[(size_t)t * 2 + 1];
    bool valid = (x >= 0) && (y >= 0);
    int top = y - 8, left = x - 8;
    top  = min(max(top, 0),  kIMG - 16);   // dynamic_slice clamp semantics
    left = min(max(left, 0), kIMG - 16);
    const float* ib = img + (size_t)b * 3 * kIMG * kIMG;
    for (int e = threadIdx.x; e < 768; e += 64) {
        int c = e >> 8, r = (e >> 4) & 15, cc = e & 15;
        float v = valid ? ib[c * kIMG * kIMG + (top + r) * kIMG + (left + cc)] : 0.f;
        pbuf[(size_t)t * 768 + e] = f2bf(v);
    }
}

// ---------------- assemble x = concat(cls, tokens) + pos_emb (fp32) ----------------
__global__ void assemble_kernel(const u16* __restrict__ tokens, const float* __restrict__ cls,
                                const float* __restrict__ pos, float* __restrict__ xb) {
    int i = blockIdx.x * 256 + threadIdx.x;
    if (i >= kM * kD) return;
    int row = i / kD, d = i - row * kD;
    int b = row / kS, s = row - b * kS;
    float v = (s == 0) ? cls[d] : bf2f(tokens[((size_t)(b * kN + s - 1)) * kD + d]);
    xb[i] = v + pos[(size_t)s * kD + d];
}

// ---------------- LayerNorm fp32 -> bf16 (D=768, block=256) ----------------
__global__ __launch_bounds__(256) void ln_kernel(const float* __restrict__ x, u16* __restrict__ outp,
                                                 const float* __restrict__ g, const float* __restrict__ bb) {
    __shared__ float sm[4];
    int row = blockIdx.x, tid = threadIdx.x;
    const float* xr = x + (size_t)row * kD;
    float v0 = xr[tid], v1 = xr[tid + 256], v2 = xr[tid + 512];
    float s = v0 + v1 + v2;
    #pragma unroll
    for (int o = 32; o > 0; o >>= 1) s += __shfl_down(s, o, 64);
    if ((tid & 63) == 0) sm[tid >> 6] = s;
    __syncthreads();
    float mu = (sm[0] + sm[1] + sm[2] + sm[3]) * (1.f / 768.f);
    __syncthreads();
    float d0 = v0 - mu, d1 = v1 - mu, d2 = v2 - mu;
    float sq = d0 * d0 + d1 * d1 + d2 * d2;
    #pragma unroll
    for (int o = 32; o > 0; o >>= 1) sq += __shfl_down(sq, o, 64);
    if ((tid & 63) == 0) sm[tid >> 6] = sq;
    __syncthreads();
    float var = (sm[0] + sm[1] + sm[2] + sm[3]) * (1.f / 768.f);
    float rs = rsqrtf(var + 1e-12f);
    u16* orow = outp + (size_t)row * kD;
    orow[tid]       = f2bf(d0 * rs * g[tid]       + bb[tid]);
    orow[tid + 256] = f2bf(d1 * rs * g[tid + 256] + bb[tid + 256]);
    orow[tid + 512] = f2bf(d2 * rs * g[tid + 512] + bb[tid + 512]);
}

// ---------------- bf16 MFMA GEMM: C[M,N] = A[M,K] @ Bt[N,K]^T (+bias, epilogue) ----------------
// EPI: 0 = bias only, 1 = bias+GELU(exact), 2 = bias+residual add
// OUTBF: 1 = bf16 out, 0 = fp32 out
template <int EPI, int OUTBF>
__global__ __launch_bounds__(256) void gemm_bt(const u16* __restrict__ A, const u16* __restrict__ Bt,
                                               u16* Cb, float* Cf,
                                               const float* __restrict__ bias, const float* resid,
                                               int N, int K) {
    __shared__ u16 sA[128 * 32];
    __shared__ u16 sB[128 * 32];
    int tid = threadIdx.x;
    int lane = tid & 63, w = tid >> 6;
    int wm = w >> 1, wn = w & 1;
    int m0 = blockIdx.x * 128, n0 = blockIdx.y * 128;
    floatx4 acc[4][4] = {};

    const int rS = tid >> 2;            // 0..63
    const int cS = (tid & 3) * 8;       // element col
    const int kq = lane >> 4;           // 0..3
    const int mr = lane & 15;

    for (int k0 = 0; k0 < K; k0 += 32) {
        __syncthreads();
        async_copy16(A  + (size_t)(m0 + rS)      * K + k0 + cS, &sA[rS * 32 + cS]);
        async_copy16(A  + (size_t)(m0 + 64 + rS) * K + k0 + cS, &sA[(64 + rS) * 32 + cS]);
        async_copy16(Bt + (size_t)(n0 + rS)      * K + k0 + cS, &sB[rS * 32 + cS]);
        async_copy16(Bt + (size_t)(n0 + 64 + rS) * K + k0 + cS, &sB[(64 + rS) * 32 + cS]);
        __syncthreads();
        short8 af[4], bf[4];
        #pragma unroll
        for (int i = 0; i < 4; i++) {
            int mloc = wm * 64 + i * 16 + mr;
            af[i] = *(const short8*)&sA[mloc * 32 + kq * 8];
            int nloc = wn * 64 + i * 16 + mr;
            bf[i] = *(const short8*)&sB[nloc * 32 + kq * 8];
        }
        #pragma unroll
        for (int i = 0; i < 4; i++)
            #pragma unroll
            for (int j = 0; j < 4; j++)
                acc[i][j] = __builtin_amdgcn_mfma_f32_16x16x32_bf16(af[i], bf[j], acc[i][j], 0, 0, 0);
    }

    int cr = (lane >> 4) * 4;   // C/D: row = (lane>>4)*4 + reg, col = lane&15
    int cc = lane & 15;
    #pragma unroll
    for (int i = 0; i < 4; i++) {
        #pragma unroll
        for (int j = 0; j < 4; j++) {
            int n = n0 + wn * 64 + j * 16 + cc;
            float bv = bias[n];
            #pragma unroll
            for (int t = 0; t < 4; t++) {
                int m = m0 + wm * 64 + i * 16 + cr + t;
                float v = acc[i][j][t] + bv;
                if (EPI == 1) v = 0.5f * v * (1.f + erff(v * 0.70710678118654752f));
                if (EPI == 2) v += resid[(size_t)m * N + n];
                if (OUTBF) Cb[(size_t)m * N + n] = f2bf(v);
                else       Cf[(size_t)m * N + n] = v;
            }
        }
    }
}

// ---------------- MFMA flash attention ----------------
// grid = (B*NH, 4). Block: 4 waves, each owns 16 queries of a 64-query tile.
// LDS: K [224][80] (b128-aligned pitch), V^T [64][224], per-wave P tile [16][32].
// Online softmax across 7 key-tiles of 32. C-layout rows sit in lane quads ->
// row reductions are shfl_xor over the low 4 lane bits.
__global__ __launch_bounds__(256) void attn_kernel(const u16* __restrict__ qkv, u16* __restrict__ outp) {
    __shared__ u16 sK[224 * 80];
    __shared__ u16 sVt[64 * 224];
    __shared__ u16 sP[4 * 16 * 32];
    int bh = blockIdx.x;
    int b = bh / kNH, h = bh % kNH;
    int tid = threadIdx.x, w = tid >> 6, lane = tid & 63;
    int mr = lane & 15, ql = lane >> 4;
    const u16* qb = qkv + (size_t)b * kS * 2304;

    // stage K [key][d]
    for (int idx = tid; idx < 197 * 8; idx += 256) {
        int r = idx >> 3, c = idx & 7;
        *(uint4*)&sK[r * 80 + c * 8] = *(const uint4*)&qb[(size_t)r * 2304 + 768 + h * 64 + c * 8];
    }
    // zero pad keys 197..223 (finite operands for the masked MFMA columns)
    for (int idx = tid; idx < 27 * 8; idx += 256) {
        int r = 197 + (idx >> 3), c = idx & 7;
        uint4 z = {0u, 0u, 0u, 0u};
        *(uint4*)&sK[r * 80 + c * 8] = z;
    }
    // stage V transposed: sVt[d][key]
    for (int idx = tid; idx < 197 * 8; idx += 256) {
        int s = idx >> 3, c = idx & 7;
        uint4 t4 = *(const uint4*)&qb[(size_t)s * 2304 + 1536 + h * 64 + c * 8];
        const u16* u = (const u16*)&t4;
        #pragma unroll
        for (int j = 0; j < 8; j++) sVt[(c * 8 + j) * 224 + s] = u[j];
    }
    for (int idx = tid; idx < 64 * 27; idx += 256) {
        int d = idx / 27, c = 197 + idx % 27;
        sVt[d * 224 + c] = 0;
    }
    __syncthreads();

    int q0 = blockIdx.y * 64 + w * 16;
    if (q0 >= kS) return;   // no further barriers — safe early exit

    int qr = q0 + mr; if (qr > 196) qr = 196;   // clamp; guarded on store
    short8 aq0 = *(const short8*)&qb[(size_t)qr * 2304 + h * 64 + ql * 8];
    short8 aq1 = *(const short8*)&qb[(size_t)qr * 2304 + h * 64 + 32 + ql * 8];

    floatx4 O0 = {}, O1 = {}, O2 = {}, O3 = {};
    float m_run[4], l_run[4];
    #pragma unroll
    for (int t = 0; t < 4; t++) { m_run[t] = -3e38f; l_run[t] = 0.f; }

    u16* myP = &sP[w * 512];
    for (int kt = 0; kt < 7; kt++) {
        int k0 = kt * 32;
        floatx4 s0 = {}, s1 = {};
        short8 bk;
        bk = *(const short8*)&sK[(k0 + mr) * 80 + ql * 8];
        s0 = __builtin_amdgcn_mfma_f32_16x16x32_bf16(aq0, bk, s0, 0, 0, 0);
        bk = *(const short8*)&sK[(k0 + mr) * 80 + 32 + ql * 8];
        s0 = __builtin_amdgcn_mfma_f32_16x16x32_bf16(aq1, bk, s0, 0, 0, 0);
        bk = *(const short8*)&sK[(k0 + 16 + mr) * 80 + ql * 8];
        s1 = __builtin_amdgcn_mfma_f32_16x16x32_bf16(aq0, bk, s1, 0, 0, 0);
        bk = *(const short8*)&sK[(k0 + 16 + mr) * 80 + 32 + ql * 8];
        s1 = __builtin_amdgcn_mfma_f32_16x16x32_bf16(aq1, bk, s1, 0, 0, 0);

        bool v0 = (k0 + mr) < kS, v1 = (k0 + 16 + mr) < kS;
        #pragma unroll
        for (int t = 0; t < 4; t++) {
            s0[t] = v0 ? s0[t] * 0.125f : -1e30f;
            s1[t] = v1 ? s1[t] * 0.125f : -1e30f;
        }
        #pragma unroll
        for (int t = 0; t < 4; t++) {
            float mt = fmaxf(s0[t], s1[t]);
            mt = fmaxf(mt, __shfl_xor(mt, 1, 64));
            mt = fmaxf(mt, __shfl_xor(mt, 2, 64));
            mt = fmaxf(mt, __shfl_xor(mt, 4, 64));
            mt = fmaxf(mt, __shfl_xor(mt, 8, 64));
            float mnew = fmaxf(m_run[t], mt);
            float alpha = __expf(m_run[t] - mnew);
            m_run[t] = mnew;
            float p0 = __expf(s0[t] - mnew);
            float p1 = __expf(s1[t] - mnew);
            float ls = p0 + p1;
            ls += __shfl_xor(ls, 1, 64);
            ls += __shfl_xor(ls, 2, 64);
            ls += __shfl_xor(ls, 4, 64);
            ls += __shfl_xor(ls, 8, 64);
            l_run[t] = l_run[t] * alpha + ls;
            O0[t] *= alpha; O1[t] *= alpha; O2[t] *= alpha; O3[t] *= alpha;
            myP[(ql * 4 + t) * 32 + mr]      = f2bf(p0);
            myP[(ql * 4 + t) * 32 + 16 + mr] = f2bf(p1);
        }
        short8 ap = *(const short8*)&myP[mr * 32 + ql * 8];   // P in A-layout
        short8 bv;
        bv = *(const short8*)&sVt[(size_t)mr * 224 + k0 + ql * 8];
        O0 = __builtin_amdgcn_mfma_f32_16x16x32_bf16(ap, bv, O0, 0, 0, 0);
        bv = *(const short8*)&sVt[(size_t)(16 + mr) * 224 + k0 + ql * 8];
        O1 = __builtin_amdgcn_mfma_f32_16x16x32_bf16(ap, bv, O1, 0, 0, 0);
        bv = *(const short8*)&sVt[(size_t)(32 + mr) * 224 + k0 + ql * 8];
        O2 = __builtin_amdgcn_mfma_f32_16x16x32_bf16(ap, bv, O2, 0, 0, 0);
        bv = *(const short8*)&sVt[(size_t)(48 + mr) * 224 + k0 + ql * 8];
        O3 = __builtin_amdgcn_mfma_f32_16x16x32_bf16(ap, bv, O3, 0, 0, 0);
    }

    #pragma unroll
    for (int t = 0; t < 4; t++) {
        int q = q0 + ql * 4 + t;
        if (q < kS) {
            float inv = 1.f / l_run[t];
            u16* orow = outp + ((size_t)b * kS + q) * kD + h * 64;
            orow[mr]      = f2bf(O0[t] * inv);
            orow[16 + mr] = f2bf(O1[t] * inv);
            orow[32 + mr] = f2bf(O2[t] * inv);
            orow[48 + mr] = f2bf(O3[t] * inv);
        }
    }
}

// ---------------- classifier ----------------
__global__ __launch_bounds__(256) void cls_kernel(const u16* __restrict__ xf, const u16* __restrict__ wb,
                                                  const float* __restrict__ cb, float* __restrict__ outp) {
    __shared__ float sx[kD];
    int b = blockIdx.x, tid = threadIdx.x;
    const u16* xr = xf + (size_t)b * kS * kD;   // CLS row
    for (int i = tid; i < kD; i += 256) sx[i] = bf2f(xr[i]);
    __syncthreads();
    for (int o = tid; o < kNL; o += 256) {
        const u16* wr = wb + (size_t)o * kD;
        float acc = 0.f;
        for (int kk = 0; kk < kD; kk += 8) {
            uint4 t4 = *(const uint4*)&wr[kk];
            const u16* u = (const u16*)&t4;
            #pragma unroll
            for (int j = 0; j < 8; j++) acc += sx[kk + j] * bf2f(u[j]);
        }
        outp[(size_t)b * kNL + o] = acc + cb[o];
    }
}

extern "C" void kernel_launch(void* const* d_in, const int* in_sizes, int n_in,
                              void* d_out, int out_size, void* d_ws, size_t ws_size,
                              hipStream_t stream) {
    const float* pixel   = (const float*)d_in[0];
    const int*   locs    = (const int*)d_in[1];
    const float* patch_w = (const float*)d_in[2];
    const float* patch_b = (const float*)d_in[3];
    const float* cls_tok = (const float*)d_in[4];
    const float* pos_emb = (const float*)d_in[5];
    const float* ln1_g   = (const float*)d_in[6];
    const float* ln1_b   = (const float*)d_in[7];
    const float* wqkv    = (const float*)d_in[8];
    const float* bqkv    = (const float*)d_in[9];
    const float* wo      = (const float*)d_in[10];
    const float* bo      = (const float*)d_in[11];
    const float* ln2_g   = (const float*)d_in[12];
    const float* ln2_b   = (const float*)d_in[13];
    const float* w1      = (const float*)d_in[14];
    const float* b1      = (const float*)d_in[15];
    const float* w2      = (const float*)d_in[16];
    const float* b2      = (const float*)d_in[17];
    const float* lnf_g   = (const float*)d_in[18];
    const float* lnf_b   = (const float*)d_in[19];
    const float* cls_w   = (const float*)d_in[20];
    const float* cls_b   = (const float*)d_in[21];
    float* out = (float*)d_out;

    char* ws = (char*)d_ws;
    float* xb  = (float*)(ws + 0);                      // [6400, 768]  fp32 residual stream
    u16*   hb  = (u16*)(ws + 19660800);                 // [6400, 768]  bf16
    u16*   big = (u16*)(ws + 29491200);                 // [6400, 3072] bf16 (qkv / mlp hidden / patches)
    u16*   wl  = (u16*)(ws + 68812800);                 // per-layer transposed weights
    u16*   pwb = (u16*)(ws + 82968576);                 // patch_w bf16 [768,768]
    u16*   cwb = (u16*)(ws + 84148224);                 // cls_w bf16 [1000,768]
    u16*   pbuf = big;                                  // gathered patches alias [6272,768]

    const size_t oQKV = 0, oWO = 1769472, oW1 = 2359296, oW2 = 4718592;

    cvt_kernel<<<2304, 256, 0, stream>>>(patch_w, pwb, 768 * 768);
    cvt_kernel<<<3000, 256, 0, stream>>>(cls_w, cwb, kNL * 768);
    gather_kernel<<<kMPATCH, 64, 0, stream>>>(pixel, locs, pbuf);
    gemm_bt<0, 1><<<dim3(49, 6), 256, 0, stream>>>(pbuf, pwb, hb, nullptr, patch_b, nullptr, 768, 768);
    assemble_kernel<<<(kM * kD + 255) / 256, 256, 0, stream>>>(hb, cls_tok, pos_emb, xb);

    for (int l = 0; l < 12; l++) {
        transpose_cvt<<<dim3(72, 24), dim3(32, 8), 0, stream>>>(wqkv + (size_t)l * 768 * 2304, wl + oQKV, 768, 2304);
        transpose_cvt<<<dim3(24, 24), dim3(32, 8), 0, stream>>>(wo   + (size_t)l * 768 * 768,  wl + oWO,  768, 768);
        transpose_cvt<<<dim3(96, 24), dim3(32, 8), 0, stream>>>(w1   + (size_t)l * 768 * 3072, wl + oW1,  768, 3072);
        transpose_cvt<<<dim3(24, 96), dim3(32, 8), 0, stream>>>(w2   + (size_t)l * 3072 * 768, wl + oW2,  3072, 768);

        ln_kernel<<<kM, 256, 0, stream>>>(xb, hb, ln1_g + l * 768, ln1_b + l * 768);
        gemm_bt<0, 1><<<dim3(50, 18), 256, 0, stream>>>(hb, wl + oQKV, big, nullptr, bqkv + (size_t)l * 2304, nullptr, 2304, 768);
        attn_kernel<<<dim3(kB * kNH, 4), 256, 0, stream>>>(big, hb);
        gemm_bt<2, 0><<<dim3(50, 6), 256, 0, stream>>>(hb, wl + oWO, nullptr, xb, bo + (size_t)l * 768, xb, 768, 768);
        ln_kernel<<<kM, 256, 0, stream>>>(xb, hb, ln2_g + l * 768, ln2_b + l * 768);
        gemm_bt<1, 1><<<dim3(50, 24), 256, 0, stream>>>(hb, wl + oW1, big, nullptr, b1 + (size_t)l * 3072, nullptr, 3072, 768);
        gemm_bt<2, 0><<<dim3(50, 6), 256, 0, stream>>>(big, wl + oW2, nullptr, xb, b2 + (size_t)l * 768, xb, 768, 3072);
    }

    ln_kernel<<<kM, 256, 0, stream>>>(xb, hb, lnf_g, lnf_b);
    cls_kernel<<<kB, 256, 0, stream>>>(hb, cwb, cls_b, out);
}